// Round 4
// baseline (15886.627 us; speedup 1.0000x reference)
//
#include <hip/hip_runtime.h>
#include <hip/hip_bf16.h>

typedef __hip_bfloat16 bf16;
typedef __attribute__((ext_vector_type(8))) short short8;
typedef __attribute__((ext_vector_type(4))) float float4v;

#define B_    1024
#define H_    512
#define G4H   2048
#define F_    32
#define CIN_  4
#define K_    30
#define STRIDE_ 6
#define L_    924
#define T_    150
#define KD_   40
#define NSTEPS_ 10
#define BH    (B_ * H_)

__device__ __forceinline__ float sigmoidf_(float x) { return 1.f / (1.f + __expf(-x)); }
__device__ __forceinline__ float tanhf_(float x)    { return 1.f - 2.f / (__expf(2.f * x) + 1.f); }
__device__ __forceinline__ float b2f_(short s) {
    return __uint_as_float(((unsigned)(unsigned short)s) << 16);
}

// ---------------------------------------------------------------------------
__global__ __launch_bounds__(256) void cvt_kernel(const float* __restrict__ src,
                                                  bf16* __restrict__ dst, int n) {
    int i = blockIdx.x * 256 + threadIdx.x;
    if (i < n) dst[i] = __float2bfloat16(src[i]);
}

__global__ void bias_kernel(const float* __restrict__ bih0, const float* __restrict__ bhh0,
                            const float* __restrict__ bih1, const float* __restrict__ bhh1,
                            float* __restrict__ b0, float* __restrict__ b1) {
    int i = blockIdx.x * 256 + threadIdx.x;
    if (i < G4H)      b0[i] = bih0[i] + bhh0[i];
    else if (i < 2*G4H) { int j = i - G4H; b1[j] = bih1[j] + bhh1[j]; }
}

// ---------------------------------------------------------------------------
// encoder conv1d + relu -> seq [T, B, F] bf16
// ---------------------------------------------------------------------------
__global__ __launch_bounds__(256) void conv_kernel(
    const float* __restrict__ x, const float* __restrict__ w,
    const float* __restrict__ cb, bf16* __restrict__ seq)
{
    __shared__ float w_lds[CIN_ * K_ * F_];
    __shared__ float x_lds[CIN_ * L_];
    int tid = threadIdx.x;
    int b = blockIdx.x;
    for (int i = tid; i < CIN_ * K_ * F_; i += 256) {
        int f = i & 31, r = i >> 5;
        w_lds[r * 32 + f] = w[f * (CIN_ * K_) + r];
    }
    const float* xb = x + (size_t)b * (CIN_ * L_);
    for (int i = tid; i < CIN_ * L_; i += 256)
        x_lds[i] = xb[i];
    __syncthreads();
    int f = tid & 31, tt = tid >> 5;
    float cbf = cb[f];
    for (int t0 = 0; t0 < T_; t0 += 8) {
        int t = t0 + tt;
        if (t < T_) {
            float acc = cbf;
            #pragma unroll
            for (int c = 0; c < CIN_; ++c) {
                const float* xr = x_lds + c * L_ + t * STRIDE_;
                const float* wr = w_lds + c * K_ * 32 + f;
                #pragma unroll
                for (int k = 0; k < K_; ++k)
                    acc += xr[k] * wr[k * 32];
            }
            acc = fmaxf(acc, 0.f);
            seq[(size_t)t * (B_ * F_) + b * F_ + f] = __float2bfloat16(acc);
        }
    }
}

// ---------------------------------------------------------------------------
// flag sync helpers (device-scope, monotonic counters in workspace)
// ---------------------------------------------------------------------------
__device__ __forceinline__ void waitf(int* f, int target) {
    if (threadIdx.x == 0) {
        while (__hip_atomic_load(f, __ATOMIC_ACQUIRE, __HIP_MEMORY_SCOPE_AGENT) < target)
            __builtin_amdgcn_s_sleep(2);
        __threadfence();
    }
    __syncthreads();
}
__device__ __forceinline__ void signalf(int* f) {
    __syncthreads();
    if (threadIdx.x == 0) {
        __threadfence();
        __hip_atomic_fetch_add(f, 1, __ATOMIC_RELEASE, __HIP_MEMORY_SCOPE_AGENT);
    }
}

// ---------------------------------------------------------------------------
// One LSTM layer step for a (m0: 256 rows) x (j0: 16 hidden cols, 4 gates) slice.
// P1KS = k-steps of the X@Wih^T part (1 for Kx=32, 16 for Kx=512); XSTR = Kx.
// Wih streamed from global; Whh fragments from LDS (resident).
// All register arrays indexed by fully-unrolled constant indices only.
// ---------------------------------------------------------------------------
template<int P1KS, int XSTR>
__device__ __forceinline__ void layer_step(
    const bf16* __restrict__ X, const bf16* __restrict__ Wih,
    const bf16* __restrict__ Hprev, const short8* __restrict__ Wlds,
    const float* __restrict__ bias, float* __restrict__ C, bf16* __restrict__ Hout,
    int m0, int j0, int wid, int lane)
{
    const int row16 = lane & 15;
    const int quad  = lane >> 4;
    const int mrow  = m0 + wid * 64 + row16;

    float4v acc[4][4];
    #pragma unroll
    for (int ms = 0; ms < 4; ++ms)
        #pragma unroll
        for (int g = 0; g < 4; ++g)
            acc[ms][g] = (float4v){0.f, 0.f, 0.f, 0.f};

    // part 1: X @ Wih^T  (B streamed from global; L1-cache reuse across waves)
    for (int ks = 0; ks < P1KS; ++ks) {
        short8 bfr[4];
        #pragma unroll
        for (int g = 0; g < 4; ++g)
            bfr[g] = *(const short8*)(Wih + (size_t)(g * H_ + j0 + row16) * XSTR
                                      + ks * 32 + quad * 8);
        short8 av[4];
        #pragma unroll
        for (int ms = 0; ms < 4; ++ms)
            av[ms] = *(const short8*)(X + (size_t)(mrow + ms * 16) * XSTR
                                      + ks * 32 + quad * 8);
        #pragma unroll
        for (int g = 0; g < 4; ++g)
            #pragma unroll
            for (int ms = 0; ms < 4; ++ms)
                acc[ms][g] = __builtin_amdgcn_mfma_f32_16x16x32_bf16(av[ms], bfr[g], acc[ms][g], 0, 0, 0);
    }

    // part 2: Hprev @ Whh^T  (B resident in LDS, frag-major)
    for (int ks = 0; ks < 16; ++ks) {
        short8 av[4];
        #pragma unroll
        for (int ms = 0; ms < 4; ++ms)
            av[ms] = *(const short8*)(Hprev + (size_t)(mrow + ms * 16) * H_
                                      + ks * 32 + quad * 8);
        #pragma unroll
        for (int g = 0; g < 4; ++g) {
            short8 bfr = Wlds[(ks * 4 + g) * 64 + lane];
            #pragma unroll
            for (int ms = 0; ms < 4; ++ms)
                acc[ms][g] = __builtin_amdgcn_mfma_f32_16x16x32_bf16(av[ms], bfr, acc[ms][g], 0, 0, 0);
        }
    }

    // epilogue
    const int j = j0 + row16;
    const float bi  = bias[j];
    const float bff = bias[H_ + j];
    const float bg  = bias[2 * H_ + j];
    const float bo  = bias[3 * H_ + j];
    #pragma unroll
    for (int ms = 0; ms < 4; ++ms) {
        #pragma unroll
        for (int r = 0; r < 4; ++r) {
            int brow = m0 + wid * 64 + ms * 16 + quad * 4 + r;
            float ig = sigmoidf_(acc[ms][0][r] + bi);
            float fg = sigmoidf_(acc[ms][1][r] + bff);
            float gg = tanhf_(acc[ms][2][r] + bg);
            float og = sigmoidf_(acc[ms][3][r] + bo);
            size_t idx = (size_t)brow * H_ + j;
            float cn = fg * C[idx] + ig * gg;
            C[idx] = cn;
            Hout[idx] = __float2bfloat16(og * tanhf_(cn));
        }
    }
}

// ---------------------------------------------------------------------------
struct PP {
    const bf16 *seq, *Wih0, *Whh0, *Wih1, *Whh1, *dwb;
    const float *b0, *b1, *dec_b;
    float *c0, *c1, *fut;
    bf16 *h0, *h1, *y;       // h0/h1: 2 slots of [B,H] each
    int *flags;              // fH0[4], fH1[4], fY[1]
};

// Persistent cooperative kernel: blocks 0..127 = layer0 (+ y/decoder duty),
// blocks 128..255 = layer1. 1 block/CU, Whh j-slice (64KB) resident in LDS.
__global__ __launch_bounds__(256, 1) void lstm_persist(PP P) {
    __shared__ short8 Wlds[4096];   // 64 KB: [ (ks*4+g)*64 + lane ]

    const int bid  = blockIdx.x;
    const bool isL0 = (bid < 128);
    const int lb   = isL0 ? bid : bid - 128;
    const int j0   = (lb & 31) * 16;
    const int mg   = lb >> 5;
    const int m0   = mg * 256;
    const int tid  = threadIdx.x;
    const int wid  = tid >> 6;
    const int lane = tid & 63;

    // stage Whh slice into LDS (frag-major)
    {
        const bf16* Whh = isL0 ? P.Whh0 : P.Whh1;
        for (int i = 0; i < 16; ++i) {
            int s = tid + i * 256;
            int frag = s >> 6, ln = s & 63;
            int ks = frag >> 2, g = frag & 3;
            Wlds[s] = *(const short8*)(Whh + (size_t)(g * H_ + j0 + (ln & 15)) * H_
                                       + ks * 32 + (ln >> 4) * 8);
        }
        __syncthreads();
    }

    int* fH0 = P.flags;
    int* fH1 = P.flags + 4;
    int* fY  = P.flags + 8;

    if (isL0) {
        // encoder t = 0..149
        for (int t = 0; t < T_; ++t) {
            waitf(fH0 + mg, 32 * t);            // peers done writing h0[t-1]
            waitf(fH1 + mg, 32 * (t - 1));      // L1 done reading slot t&1 (t-2 phase)
            layer_step<1, 32>(P.seq + (size_t)t * B_ * F_, P.Wih0,
                              P.h0 + ((t + 1) & 1) * BH, Wlds, P.b0,
                              P.c0, P.h0 + (t & 1) * BH, m0, j0, wid, lane);
            signalf(fH0 + mg);
        }
        // decoder: interleave y-rounds and L0 steps
        for (int s = 0; s <= NSTEPS_; ++s) {
            // y-round s: y = h1[149+s] @ dec_w^T + dec_b
            waitf(fH1 + mg, 32 * (T_ + s));
            {
                int id = bid * 256 + tid;       // 0..32767
                int br = id >> 5, f = id & 31;
                const short8* hv = (const short8*)(P.h1 + (size_t)((T_ - 1 + s) & 1) * BH
                                                   + (size_t)br * H_);
                const short8* wv = (const short8*)(P.dwb + (size_t)f * H_);
                float acc = P.dec_b[f];
                for (int i = 0; i < H_ / 8; ++i) {
                    short8 h8 = hv[i], w8 = wv[i];
                    #pragma unroll
                    for (int k = 0; k < 8; ++k)
                        acc += b2f_(h8[k]) * b2f_(w8[k]);
                }
                P.y[id] = __float2bfloat16(acc);
                if (s >= 1)
                    P.fut[(size_t)br * (F_ * NSTEPS_) + f * NSTEPS_ + (s - 1)] = acc;
            }
            signalf(fY);
            if (s < NSTEPS_) {
                int t = T_ + s;
                waitf(fY, 128 * (s + 1));       // all y-blocks done round s
                waitf(fH0 + mg, 32 * t);        // self-group previous step
                layer_step<1, 32>(P.y, P.Wih0,
                                  P.h0 + ((t + 1) & 1) * BH, Wlds, P.b0,
                                  P.c0, P.h0 + (t & 1) * BH, m0, j0, wid, lane);
                signalf(fH0 + mg);
            }
        }
    } else {
        // layer 1: t = 0..159
        for (int t = 0; t < T_ + NSTEPS_; ++t) {
            waitf(fH0 + mg, 32 * (t + 1));      // h0[t] ready
            waitf(fH1 + mg, 32 * t);            // peers done h1[t-1]
            layer_step<16, 512>(P.h0 + (size_t)(t & 1) * BH, P.Wih1,
                                P.h1 + (size_t)((t + 1) & 1) * BH, Wlds, P.b1,
                                P.c1, P.h1 + (size_t)(t & 1) * BH, m0, j0, wid, lane);
            signalf(fH1 + mg);
        }
    }
}

// ---------------------------------------------------------------------------
__global__ __launch_bounds__(256) void deconv_kernel(
    const float* __restrict__ fut, const float* __restrict__ dw,
    float* __restrict__ out)
{
    int idx = blockIdx.x * 256 + threadIdx.x;
    if (idx >= B_ * 49) return;
    int b = idx / 49, jj = idx % 49;
    int tlo = jj - (KD_ - 1); if (tlo < 0) tlo = 0;
    int thi = jj; if (thi > NSTEPS_ - 1) thi = NSTEPS_ - 1;
    float acc = 0.f;
    for (int f = 0; f < F_; ++f) {
        const float* fr = fut + (size_t)b * (F_ * NSTEPS_) + f * NSTEPS_;
        const float* wr = dw + f * KD_;
        for (int t = tlo; t <= thi; ++t)
            acc += fr[t] * wr[jj - t];
    }
    out[idx] = acc;
}

// ---------------------------------------------------------------------------
extern "C" void kernel_launch(void* const* d_in, const int* in_sizes, int n_in,
                              void* d_out, int out_size, void* d_ws, size_t ws_size,
                              hipStream_t stream) {
    const float* x       = (const float*)d_in[0];
    const float* conv_w  = (const float*)d_in[1];
    const float* conv_b  = (const float*)d_in[2];
    const float* Wih0f   = (const float*)d_in[3];
    const float* Whh0f   = (const float*)d_in[4];
    const float* bih0    = (const float*)d_in[5];
    const float* bhh0    = (const float*)d_in[6];
    const float* Wih1f   = (const float*)d_in[7];
    const float* Whh1f   = (const float*)d_in[8];
    const float* bih1    = (const float*)d_in[9];
    const float* bhh1    = (const float*)d_in[10];
    const float* dec_wf  = (const float*)d_in[11];
    const float* dec_b   = (const float*)d_in[12];
    const float* deconvw = (const float*)d_in[13];
    float* out = (float*)d_out;

    char* ws = (char*)d_ws;
    size_t off = 0;
    auto alloc = [&](size_t bytes) { char* p = ws + off; off = (off + bytes + 255) & ~(size_t)255; return p; };
    bf16*  seq   = (bf16*) alloc((size_t)T_ * B_ * F_ * 2);
    float* b0v   = (float*)alloc(G4H * 4);
    float* b1v   = (float*)alloc(G4H * 4);
    float* c0    = (float*)alloc((size_t)BH * 4);
    float* c1    = (float*)alloc((size_t)BH * 4);
    bf16*  h0    = (bf16*) alloc((size_t)2 * BH * 2);
    bf16*  h1    = (bf16*) alloc((size_t)2 * BH * 2);
    bf16*  y     = (bf16*) alloc((size_t)B_ * F_ * 2);
    float* fut   = (float*)alloc((size_t)B_ * F_ * NSTEPS_ * 4);
    bf16*  Wih0b = (bf16*) alloc((size_t)G4H * F_ * 2);
    bf16*  Whh0b = (bf16*) alloc((size_t)G4H * H_ * 2);
    bf16*  Wih1b = (bf16*) alloc((size_t)G4H * H_ * 2);
    bf16*  Whh1b = (bf16*) alloc((size_t)G4H * H_ * 2);
    bf16*  dec_wb= (bf16*) alloc((size_t)F_ * H_ * 2);
    int*   flags = (int*)  alloc(64 * 4);

    hipMemsetAsync(c0, 0, (size_t)BH * 4, stream);
    hipMemsetAsync(c1, 0, (size_t)BH * 4, stream);
    hipMemsetAsync(h0, 0, (size_t)2 * BH * 2, stream);
    hipMemsetAsync(h1, 0, (size_t)2 * BH * 2, stream);
    hipMemsetAsync(flags, 0, 64 * 4, stream);

    cvt_kernel<<<(G4H * F_ + 255) / 256, 256, 0, stream>>>(Wih0f, Wih0b, G4H * F_);
    cvt_kernel<<<(G4H * H_ + 255) / 256, 256, 0, stream>>>(Whh0f, Whh0b, G4H * H_);
    cvt_kernel<<<(G4H * H_ + 255) / 256, 256, 0, stream>>>(Wih1f, Wih1b, G4H * H_);
    cvt_kernel<<<(G4H * H_ + 255) / 256, 256, 0, stream>>>(Whh1f, Whh1b, G4H * H_);
    cvt_kernel<<<(F_ * H_ + 255) / 256, 256, 0, stream>>>(dec_wf, dec_wb, F_ * H_);

    bias_kernel<<<16, 256, 0, stream>>>(bih0, bhh0, bih1, bhh1, b0v, b1v);
    conv_kernel<<<B_, 256, 0, stream>>>(x, conv_w, conv_b, seq);

    PP P;
    P.seq = seq; P.Wih0 = Wih0b; P.Whh0 = Whh0b; P.Wih1 = Wih1b; P.Whh1 = Whh1b;
    P.dwb = dec_wb; P.b0 = b0v; P.b1 = b1v; P.dec_b = dec_b;
    P.c0 = c0; P.c1 = c1; P.fut = fut; P.h0 = h0; P.h1 = h1; P.y = y;
    P.flags = flags;

    void* args[] = { &P };
    hipError_t err = hipLaunchCooperativeKernel((const void*)lstm_persist,
                                                dim3(256), dim3(256), args, 0, stream);
    if (err != hipSuccess) {
        // fallback: plain launch (256 blocks, 1/CU -> co-resident in practice)
        lstm_persist<<<256, 256, 0, stream>>>(P);
    }

    deconv_kernel<<<196, 256, 0, stream>>>(fut, deconvw, out);
}

// Round 5
// 11010.316 us; speedup vs baseline: 1.4429x; 1.4429x over previous
//
#include <hip/hip_runtime.h>
#include <hip/hip_bf16.h>

typedef __hip_bfloat16 bf16;
typedef __attribute__((ext_vector_type(8))) short short8;
typedef __attribute__((ext_vector_type(4))) float float4v;

#define B_    1024
#define H_    512
#define G4H   2048
#define F_    32
#define CIN_  4
#define K_    30
#define STRIDE_ 6
#define L_    924
#define T_    150
#define KD_   40
#define NSTEPS_ 10
#define BH    (B_ * H_)
#define STRF  16   // ints between flags = 64B (one cacheline per flag)

__device__ __forceinline__ float sigmoidf_(float x) { return 1.f / (1.f + __expf(-x)); }
__device__ __forceinline__ float tanhf_(float x)    { return 1.f - 2.f / (__expf(2.f * x) + 1.f); }
__device__ __forceinline__ float b2f_(short s) {
    return __uint_as_float(((unsigned)(unsigned short)s) << 16);
}

// ---------------------------------------------------------------------------
__global__ __launch_bounds__(256) void cvt_kernel(const float* __restrict__ src,
                                                  bf16* __restrict__ dst, int n) {
    int i = blockIdx.x * 256 + threadIdx.x;
    if (i < n) dst[i] = __float2bfloat16(src[i]);
}

__global__ void bias_kernel(const float* __restrict__ bih0, const float* __restrict__ bhh0,
                            const float* __restrict__ bih1, const float* __restrict__ bhh1,
                            float* __restrict__ b0, float* __restrict__ b1) {
    int i = blockIdx.x * 256 + threadIdx.x;
    if (i < G4H)      b0[i] = bih0[i] + bhh0[i];
    else if (i < 2*G4H) { int j = i - G4H; b1[j] = bih1[j] + bhh1[j]; }
}

// ---------------------------------------------------------------------------
// encoder conv1d + relu -> seq [T, B, F] bf16
// ---------------------------------------------------------------------------
__global__ __launch_bounds__(256) void conv_kernel(
    const float* __restrict__ x, const float* __restrict__ w,
    const float* __restrict__ cb, bf16* __restrict__ seq)
{
    __shared__ float w_lds[CIN_ * K_ * F_];
    __shared__ float x_lds[CIN_ * L_];
    int tid = threadIdx.x;
    int b = blockIdx.x;
    for (int i = tid; i < CIN_ * K_ * F_; i += 256) {
        int f = i & 31, r = i >> 5;
        w_lds[r * 32 + f] = w[f * (CIN_ * K_) + r];
    }
    const float* xb = x + (size_t)b * (CIN_ * L_);
    for (int i = tid; i < CIN_ * L_; i += 256)
        x_lds[i] = xb[i];
    __syncthreads();
    int f = tid & 31, tt = tid >> 5;
    float cbf = cb[f];
    for (int t0 = 0; t0 < T_; t0 += 8) {
        int t = t0 + tt;
        if (t < T_) {
            float acc = cbf;
            #pragma unroll
            for (int c = 0; c < CIN_; ++c) {
                const float* xr = x_lds + c * L_ + t * STRIDE_;
                const float* wr = w_lds + c * K_ * 32 + f;
                #pragma unroll
                for (int k = 0; k < K_; ++k)
                    acc += xr[k] * wr[k * 32];
            }
            acc = fmaxf(acc, 0.f);
            seq[(size_t)t * (B_ * F_) + b * F_ + f] = __float2bfloat16(acc);
        }
    }
}

// ---------------------------------------------------------------------------
// sync: per-block flags (release-store, no RMW), wave-parallel read-only polls.
// Wave 0: lanes 0..31 poll fa[lane], lanes 32..63 poll fb[lane-32]; exit when
// ALL observed values >= their targets. Flags are 64B apart (own cacheline).
// ---------------------------------------------------------------------------
__device__ __forceinline__ void wait2(const int* fa, int ta, const int* fb, int tb) {
    const int t = threadIdx.x;
    if (t < 64) {
        const int* p = nullptr; int tgt;
        if (t < 32) { if (fa) p = fa + t * STRF;        tgt = ta; }
        else        { if (fb) p = fb + (t - 32) * STRF; tgt = tb; }
        for (;;) {
            int v = p ? __hip_atomic_load(p, __ATOMIC_RELAXED, __HIP_MEMORY_SCOPE_AGENT)
                      : 0x7fffffff;
            if (__all(v >= tgt)) break;
            __builtin_amdgcn_s_sleep(8);
        }
    }
    __syncthreads();
    __threadfence();   // acquire: fresh view of produced data for ALL threads
}

__device__ __forceinline__ void signal1(int* f, int val) {
    __syncthreads();
    if (threadIdx.x == 0) {
        __threadfence();   // release: drain this block's writes agent-wide
        __hip_atomic_store(f, val, __ATOMIC_RELAXED, __HIP_MEMORY_SCOPE_AGENT);
    }
}

// ---------------------------------------------------------------------------
// One LSTM layer step for a (m0: 256 rows) x (j0: 16 hidden cols, 4 gates) slice.
// P1KS = k-steps of the X@Wih^T part (1 for Kx=32, 16 for Kx=512); XSTR = Kx.
// Wih streamed from global (L2-hot); Whh fragments from LDS (resident).
// All register arrays indexed by fully-unrolled constant indices only.
// ---------------------------------------------------------------------------
template<int P1KS, int XSTR>
__device__ __forceinline__ void layer_step(
    const bf16* __restrict__ X, const bf16* __restrict__ Wih,
    const bf16* __restrict__ Hprev, const short8* __restrict__ Wlds,
    const float* __restrict__ bias, float* __restrict__ C, bf16* __restrict__ Hout,
    int m0, int j0, int wid, int lane)
{
    const int row16 = lane & 15;
    const int quad  = lane >> 4;
    const int mrow  = m0 + wid * 64 + row16;

    float4v acc[4][4];
    #pragma unroll
    for (int ms = 0; ms < 4; ++ms)
        #pragma unroll
        for (int g = 0; g < 4; ++g)
            acc[ms][g] = (float4v){0.f, 0.f, 0.f, 0.f};

    // part 1: X @ Wih^T
    for (int ks = 0; ks < P1KS; ++ks) {
        short8 bfr[4];
        #pragma unroll
        for (int g = 0; g < 4; ++g)
            bfr[g] = *(const short8*)(Wih + (size_t)(g * H_ + j0 + row16) * XSTR
                                      + ks * 32 + quad * 8);
        short8 av[4];
        #pragma unroll
        for (int ms = 0; ms < 4; ++ms)
            av[ms] = *(const short8*)(X + (size_t)(mrow + ms * 16) * XSTR
                                      + ks * 32 + quad * 8);
        #pragma unroll
        for (int g = 0; g < 4; ++g)
            #pragma unroll
            for (int ms = 0; ms < 4; ++ms)
                acc[ms][g] = __builtin_amdgcn_mfma_f32_16x16x32_bf16(av[ms], bfr[g], acc[ms][g], 0, 0, 0);
    }

    // part 2: Hprev @ Whh^T (Whh resident in LDS, frag-major)
    for (int ks = 0; ks < 16; ++ks) {
        short8 av[4];
        #pragma unroll
        for (int ms = 0; ms < 4; ++ms)
            av[ms] = *(const short8*)(Hprev + (size_t)(mrow + ms * 16) * H_
                                      + ks * 32 + quad * 8);
        #pragma unroll
        for (int g = 0; g < 4; ++g) {
            short8 bfr = Wlds[(ks * 4 + g) * 64 + lane];
            #pragma unroll
            for (int ms = 0; ms < 4; ++ms)
                acc[ms][g] = __builtin_amdgcn_mfma_f32_16x16x32_bf16(av[ms], bfr, acc[ms][g], 0, 0, 0);
        }
    }

    // epilogue
    const int j = j0 + row16;
    const float bi  = bias[j];
    const float bff = bias[H_ + j];
    const float bg  = bias[2 * H_ + j];
    const float bo  = bias[3 * H_ + j];
    #pragma unroll
    for (int ms = 0; ms < 4; ++ms) {
        #pragma unroll
        for (int r = 0; r < 4; ++r) {
            int brow = m0 + wid * 64 + ms * 16 + quad * 4 + r;
            float ig = sigmoidf_(acc[ms][0][r] + bi);
            float fg = sigmoidf_(acc[ms][1][r] + bff);
            float gg = tanhf_(acc[ms][2][r] + bg);
            float og = sigmoidf_(acc[ms][3][r] + bo);
            size_t idx = (size_t)brow * H_ + j;
            float cn = fg * C[idx] + ig * gg;
            C[idx] = cn;
            Hout[idx] = __float2bfloat16(og * tanhf_(cn));
        }
    }
}

// ---------------------------------------------------------------------------
struct PP {
    const bf16 *seq, *Wih0, *Whh0, *Wih1, *Whh1, *dwb;
    const float *b0, *b1, *dec_b;
    float *c0, *c1, *fut;
    bf16 *h0, *h1, *y;       // h0/h1: 2 slots of [B,H] each
    int *flags;              // f0[128], f1[128], fy[128], each 64B apart
};

// Persistent kernel: blocks 0..127 = layer0 (+ y/decoder duty),
// blocks 128..255 = layer1. 1 block/CU, Whh j-slice (64KB) resident in LDS.
// Block (mg = lb>>5, jj = lb&31): rows mg*256..+255, cols jj*16..+15.
__global__ __launch_bounds__(256, 1) void lstm_persist(PP P) {
    __shared__ short8 Wlds[4096];   // 64 KB: [ (ks*4+g)*64 + lane ]

    const int bid  = blockIdx.x;
    const bool isL0 = (bid < 128);
    const int lb   = isL0 ? bid : bid - 128;
    const int j0   = (lb & 31) * 16;
    const int mg   = lb >> 5;
    const int m0   = mg * 256;
    const int tid  = threadIdx.x;
    const int wid  = tid >> 6;
    const int lane = tid & 63;

    // stage Whh slice into LDS (frag-major)
    {
        const bf16* Whh = isL0 ? P.Whh0 : P.Whh1;
        for (int i = 0; i < 16; ++i) {
            int s = tid + i * 256;
            int frag = s >> 6, ln = s & 63;
            int ks = frag >> 2, g = frag & 3;
            Wlds[s] = *(const short8*)(Whh + (size_t)(g * H_ + j0 + (ln & 15)) * H_
                                       + ks * 32 + (ln >> 4) * 8);
        }
        __syncthreads();
    }

    int* f0 = P.flags;                 // layer0 step flags, value = t+1
    int* f1 = P.flags + 128 * STRF;    // layer1 step flags
    int* fy = P.flags + 256 * STRF;    // y-round flags, value = s+1
    const int* f0g = f0 + mg * 32 * STRF;   // own m-group's 32 flags
    const int* f1g = f1 + mg * 32 * STRF;
    const int* fyg = fy + mg * 32 * STRF;

    if (isL0) {
        // encoder t = 0..149
        for (int t = 0; t < T_; ++t) {
            // peers done h0[t-1] (Hprev needs all 512 cols); L1 done with slot (t-2)
            wait2(f0g, t, f1g, t - 1);
            layer_step<1, 32>(P.seq + (size_t)t * B_ * F_, P.Wih0,
                              P.h0 + ((t + 1) & 1) * BH, Wlds, P.b0,
                              P.c0, P.h0 + (t & 1) * BH, m0, j0, wid, lane);
            signal1(f0 + lb * STRF, t + 1);
        }
        // decoder: interleave y-rounds and L0 steps
        for (int s = 0; s <= NSTEPS_; ++s) {
            // y-round s: needs h1[T-1+s] fully written by own-mg L1 blocks
            wait2(f1g, T_ + s, nullptr, 0);
            {
                int id = lb * 256 + tid;        // 0..32767 = b*32 + f
                int br = id >> 5, f = id & 31;
                const short8* hv = (const short8*)(P.h1 + (size_t)((T_ - 1 + s) & 1) * BH
                                                   + (size_t)br * H_);
                const short8* wv = (const short8*)(P.dwb + (size_t)f * H_);
                float acc = P.dec_b[f];
                for (int i = 0; i < H_ / 8; ++i) {
                    short8 h8 = hv[i], w8 = wv[i];
                    #pragma unroll
                    for (int k = 0; k < 8; ++k)
                        acc += b2f_(h8[k]) * b2f_(w8[k]);
                }
                P.y[id] = __float2bfloat16(acc);
                if (s >= 1)
                    P.fut[(size_t)br * (F_ * NSTEPS_) + f * NSTEPS_ + (s - 1)] = acc;
            }
            signal1(fy + lb * STRF, s + 1);
            if (s < NSTEPS_) {
                int t = T_ + s;
                // peers done h0[t-1]; y rows of own mg written this round
                wait2(f0g, t, fyg, s + 1);
                layer_step<1, 32>(P.y, P.Wih0,
                                  P.h0 + ((t + 1) & 1) * BH, Wlds, P.b0,
                                  P.c0, P.h0 + (t & 1) * BH, m0, j0, wid, lane);
                signal1(f0 + lb * STRF, t + 1);
            }
        }
    } else {
        // layer 1: t = 0..159  (X = h0[t] always, incl. decoder)
        for (int t = 0; t < T_ + NSTEPS_; ++t) {
            // h0[t] ready from own-mg L0 blocks; peers done h1[t-1] (slot + Hprev)
            wait2(f0g, t + 1, f1g, t);
            layer_step<16, 512>(P.h0 + (size_t)(t & 1) * BH, P.Wih1,
                                P.h1 + (size_t)((t + 1) & 1) * BH, Wlds, P.b1,
                                P.c1, P.h1 + (size_t)(t & 1) * BH, m0, j0, wid, lane);
            signal1(f1 + lb * STRF, t + 1);
        }
    }
}

// ---------------------------------------------------------------------------
__global__ __launch_bounds__(256) void deconv_kernel(
    const float* __restrict__ fut, const float* __restrict__ dw,
    float* __restrict__ out)
{
    int idx = blockIdx.x * 256 + threadIdx.x;
    if (idx >= B_ * 49) return;
    int b = idx / 49, jj = idx % 49;
    int tlo = jj - (KD_ - 1); if (tlo < 0) tlo = 0;
    int thi = jj; if (thi > NSTEPS_ - 1) thi = NSTEPS_ - 1;
    float acc = 0.f;
    for (int f = 0; f < F_; ++f) {
        const float* fr = fut + (size_t)b * (F_ * NSTEPS_) + f * NSTEPS_;
        const float* wr = dw + f * KD_;
        for (int t = tlo; t <= thi; ++t)
            acc += fr[t] * wr[jj - t];
    }
    out[idx] = acc;
}

// ---------------------------------------------------------------------------
extern "C" void kernel_launch(void* const* d_in, const int* in_sizes, int n_in,
                              void* d_out, int out_size, void* d_ws, size_t ws_size,
                              hipStream_t stream) {
    const float* x       = (const float*)d_in[0];
    const float* conv_w  = (const float*)d_in[1];
    const float* conv_b  = (const float*)d_in[2];
    const float* Wih0f   = (const float*)d_in[3];
    const float* Whh0f   = (const float*)d_in[4];
    const float* bih0    = (const float*)d_in[5];
    const float* bhh0    = (const float*)d_in[6];
    const float* Wih1f   = (const float*)d_in[7];
    const float* Whh1f   = (const float*)d_in[8];
    const float* bih1    = (const float*)d_in[9];
    const float* bhh1    = (const float*)d_in[10];
    const float* dec_wf  = (const float*)d_in[11];
    const float* dec_b   = (const float*)d_in[12];
    const float* deconvw = (const float*)d_in[13];
    float* out = (float*)d_out;

    char* ws = (char*)d_ws;
    size_t off = 0;
    auto alloc = [&](size_t bytes) { char* p = ws + off; off = (off + bytes + 255) & ~(size_t)255; return p; };
    bf16*  seq   = (bf16*) alloc((size_t)T_ * B_ * F_ * 2);
    float* b0v   = (float*)alloc(G4H * 4);
    float* b1v   = (float*)alloc(G4H * 4);
    float* c0    = (float*)alloc((size_t)BH * 4);
    float* c1    = (float*)alloc((size_t)BH * 4);
    bf16*  h0    = (bf16*) alloc((size_t)2 * BH * 2);
    bf16*  h1    = (bf16*) alloc((size_t)2 * BH * 2);
    bf16*  y     = (bf16*) alloc((size_t)B_ * F_ * 2);
    float* fut   = (float*)alloc((size_t)B_ * F_ * NSTEPS_ * 4);
    bf16*  Wih0b = (bf16*) alloc((size_t)G4H * F_ * 2);
    bf16*  Whh0b = (bf16*) alloc((size_t)G4H * H_ * 2);
    bf16*  Wih1b = (bf16*) alloc((size_t)G4H * H_ * 2);
    bf16*  Whh1b = (bf16*) alloc((size_t)G4H * H_ * 2);
    bf16*  dec_wb= (bf16*) alloc((size_t)F_ * H_ * 2);
    int*   flags = (int*)  alloc(3 * 128 * STRF * 4);

    hipMemsetAsync(c0, 0, (size_t)BH * 4, stream);
    hipMemsetAsync(c1, 0, (size_t)BH * 4, stream);
    hipMemsetAsync(h0, 0, (size_t)2 * BH * 2, stream);
    hipMemsetAsync(h1, 0, (size_t)2 * BH * 2, stream);
    hipMemsetAsync(flags, 0, 3 * 128 * STRF * 4, stream);

    cvt_kernel<<<(G4H * F_ + 255) / 256, 256, 0, stream>>>(Wih0f, Wih0b, G4H * F_);
    cvt_kernel<<<(G4H * H_ + 255) / 256, 256, 0, stream>>>(Whh0f, Whh0b, G4H * H_);
    cvt_kernel<<<(G4H * H_ + 255) / 256, 256, 0, stream>>>(Wih1f, Wih1b, G4H * H_);
    cvt_kernel<<<(G4H * H_ + 255) / 256, 256, 0, stream>>>(Whh1f, Whh1b, G4H * H_);
    cvt_kernel<<<(F_ * H_ + 255) / 256, 256, 0, stream>>>(dec_wf, dec_wb, F_ * H_);

    bias_kernel<<<16, 256, 0, stream>>>(bih0, bhh0, bih1, bhh1, b0v, b1v);
    conv_kernel<<<B_, 256, 0, stream>>>(x, conv_w, conv_b, seq);

    PP P;
    P.seq = seq; P.Wih0 = Wih0b; P.Whh0 = Whh0b; P.Wih1 = Wih1b; P.Whh1 = Whh1b;
    P.dwb = dec_wb; P.b0 = b0v; P.b1 = b1v; P.dec_b = dec_b;
    P.c0 = c0; P.c1 = c1; P.fut = fut; P.h0 = h0; P.h1 = h1; P.y = y;
    P.flags = flags;

    void* args[] = { &P };
    hipError_t err = hipLaunchCooperativeKernel((const void*)lstm_persist,
                                                dim3(256), dim3(256), args, 0, stream);
    if (err != hipSuccess) {
        lstm_persist<<<256, 256, 0, stream>>>(P);
    }

    deconv_kernel<<<196, 256, 0, stream>>>(fut, deconvw, out);
}

// Round 6
// 7373.013 us; speedup vs baseline: 2.1547x; 1.4933x over previous
//
#include <hip/hip_runtime.h>
#include <hip/hip_bf16.h>

typedef __hip_bfloat16 bf16;
typedef __attribute__((ext_vector_type(8))) short short8;
typedef __attribute__((ext_vector_type(4))) float float4v;

#define B_    1024
#define H_    512
#define G4H   2048
#define F_    32
#define CIN_  4
#define K_    30
#define STRIDE_ 6
#define L_    924
#define T_    150
#define KD_   40
#define NSTEPS_ 10
#define BH    (B_ * H_)
#define STRF  16   // ints between flags = 64B (one cacheline per flag)

__device__ __forceinline__ float sigmoidf_(float x) { return 1.f / (1.f + __expf(-x)); }
__device__ __forceinline__ float tanhf_(float x)    { return 1.f - 2.f / (__expf(2.f * x) + 1.f); }
__device__ __forceinline__ float b2f_(short s) {
    return __uint_as_float(((unsigned)(unsigned short)s) << 16);
}

// ---------------------------------------------------------------------------
__global__ __launch_bounds__(256) void cvt_kernel(const float* __restrict__ src,
                                                  bf16* __restrict__ dst, int n) {
    int i = blockIdx.x * 256 + threadIdx.x;
    if (i < n) dst[i] = __float2bfloat16(src[i]);
}

__global__ void bias_kernel(const float* __restrict__ bih0, const float* __restrict__ bhh0,
                            const float* __restrict__ bih1, const float* __restrict__ bhh1,
                            float* __restrict__ b0, float* __restrict__ b1) {
    int i = blockIdx.x * 256 + threadIdx.x;
    if (i < G4H)      b0[i] = bih0[i] + bhh0[i];
    else if (i < 2*G4H) { int j = i - G4H; b1[j] = bih1[j] + bhh1[j]; }
}

// ---------------------------------------------------------------------------
__global__ __launch_bounds__(256) void conv_kernel(
    const float* __restrict__ x, const float* __restrict__ w,
    const float* __restrict__ cb, bf16* __restrict__ seq)
{
    __shared__ float w_lds[CIN_ * K_ * F_];
    __shared__ float x_lds[CIN_ * L_];
    int tid = threadIdx.x;
    int b = blockIdx.x;
    for (int i = tid; i < CIN_ * K_ * F_; i += 256) {
        int f = i & 31, r = i >> 5;
        w_lds[r * 32 + f] = w[f * (CIN_ * K_) + r];
    }
    const float* xb = x + (size_t)b * (CIN_ * L_);
    for (int i = tid; i < CIN_ * L_; i += 256)
        x_lds[i] = xb[i];
    __syncthreads();
    int f = tid & 31, tt = tid >> 5;
    float cbf = cb[f];
    for (int t0 = 0; t0 < T_; t0 += 8) {
        int t = t0 + tt;
        if (t < T_) {
            float acc = cbf;
            #pragma unroll
            for (int c = 0; c < CIN_; ++c) {
                const float* xr = x_lds + c * L_ + t * STRIDE_;
                const float* wr = w_lds + c * K_ * 32 + f;
                #pragma unroll
                for (int k = 0; k < K_; ++k)
                    acc += xr[k] * wr[k * 32];
            }
            acc = fmaxf(acc, 0.f);
            seq[(size_t)t * (B_ * F_) + b * F_ + f] = __float2bfloat16(acc);
        }
    }
}

// ---------------------------------------------------------------------------
// sync: per-block padded flags, release-store, wave-parallel read-only polls.
// ---------------------------------------------------------------------------
__device__ __forceinline__ void wait2(const int* fa, int ta, const int* fb, int tb) {
    const int t = threadIdx.x;
    if (t < 64) {
        const int* p = nullptr; int tgt = 0;
        if (t < 32) { if (fa) { p = fa + t * STRF;        tgt = ta; } }
        else        { if (fb) { p = fb + (t - 32) * STRF; tgt = tb; } }
        for (;;) {
            int v = p ? __hip_atomic_load(p, __ATOMIC_RELAXED, __HIP_MEMORY_SCOPE_AGENT)
                      : 0x7fffffff;
            if (__all(v >= tgt)) break;
            __builtin_amdgcn_s_sleep(2);
        }
    }
    __syncthreads();
    __threadfence();   // acquire: invalidate stale cached producer data
}

__device__ __forceinline__ void signal1(int* f, int val) {
    __syncthreads();
    if (threadIdx.x == 0) {
        __threadfence();   // release: drain this block's writes agent-wide
        __hip_atomic_store(f, val, __ATOMIC_RELAXED, __HIP_MEMORY_SCOPE_AGENT);
    }
}

// ---------------------------------------------------------------------------
// One layer step for (m0: 256 rows) x (j0: 16 cols, 4 gates).
// Wih AND Whh both LDS-resident (WldsI / WldsH). C state lives in registers.
// P1KS: k-steps of X part (1 for Kx=32, 16 for Kx=512). XSTR = Kx.
// ---------------------------------------------------------------------------
template<int P1KS, int XSTR>
__device__ __forceinline__ void layer_step(
    const bf16* __restrict__ X, const bf16* __restrict__ Hprev,
    const short8* __restrict__ WldsH, const short8* __restrict__ WldsI,
    const float* __restrict__ bias, float (&creg)[16], bf16* __restrict__ Hout,
    int m0, int j0, int wid, int lane)
{
    const int row16 = lane & 15;
    const int quad  = lane >> 4;
    const int mrow  = m0 + wid * 64 + row16;

    float4v acc[4][4];
    #pragma unroll
    for (int ms = 0; ms < 4; ++ms)
        #pragma unroll
        for (int g = 0; g < 4; ++g)
            acc[ms][g] = (float4v){0.f, 0.f, 0.f, 0.f};

    // part 1: X @ Wih^T (B from LDS)
    for (int ks = 0; ks < P1KS; ++ks) {
        short8 av[4];
        #pragma unroll
        for (int ms = 0; ms < 4; ++ms)
            av[ms] = *(const short8*)(X + (size_t)(mrow + ms * 16) * XSTR
                                      + ks * 32 + quad * 8);
        #pragma unroll
        for (int g = 0; g < 4; ++g) {
            short8 bfr = WldsI[(ks * 4 + g) * 64 + lane];
            #pragma unroll
            for (int ms = 0; ms < 4; ++ms)
                acc[ms][g] = __builtin_amdgcn_mfma_f32_16x16x32_bf16(av[ms], bfr, acc[ms][g], 0, 0, 0);
        }
    }

    // part 2: Hprev @ Whh^T (B from LDS)
    for (int ks = 0; ks < 16; ++ks) {
        short8 av[4];
        #pragma unroll
        for (int ms = 0; ms < 4; ++ms)
            av[ms] = *(const short8*)(Hprev + (size_t)(mrow + ms * 16) * H_
                                      + ks * 32 + quad * 8);
        #pragma unroll
        for (int g = 0; g < 4; ++g) {
            short8 bfr = WldsH[(ks * 4 + g) * 64 + lane];
            #pragma unroll
            for (int ms = 0; ms < 4; ++ms)
                acc[ms][g] = __builtin_amdgcn_mfma_f32_16x16x32_bf16(av[ms], bfr, acc[ms][g], 0, 0, 0);
        }
    }

    // epilogue: c in registers
    const int j = j0 + row16;
    const float bi  = bias[j];
    const float bff = bias[H_ + j];
    const float bg  = bias[2 * H_ + j];
    const float bo  = bias[3 * H_ + j];
    #pragma unroll
    for (int ms = 0; ms < 4; ++ms) {
        #pragma unroll
        for (int r = 0; r < 4; ++r) {
            int brow = m0 + wid * 64 + ms * 16 + quad * 4 + r;
            float ig = sigmoidf_(acc[ms][0][r] + bi);
            float fg = sigmoidf_(acc[ms][1][r] + bff);
            float gg = tanhf_(acc[ms][2][r] + bg);
            float og = sigmoidf_(acc[ms][3][r] + bo);
            float cn = fg * creg[ms * 4 + r] + ig * gg;
            creg[ms * 4 + r] = cn;
            Hout[(size_t)brow * H_ + j] = __float2bfloat16(og * tanhf_(cn));
        }
    }
}

// ---------------------------------------------------------------------------
struct PP {
    const bf16 *seq, *Wih0, *Whh0, *Wih1, *Whh1, *dwb;
    const float *b0, *b1, *dec_b;
    float *fut;
    bf16 *h0, *h1, *y;       // h0/h1: 3 slots of [B,H] each
    int *flags;              // f0[128], f1[128], fy[128], 64B apart
};

// Persistent kernel, 256 blocks (1/CU). Swizzle: bid = jj*8 + layer*4 + mg
// so each (layer,mg) peer group (shares h-slice reads) sits on one XCD.
// flag value = t+1 when step t complete. 3 h-slots (slot = t%3):
//   L0(t): wait peers f0>=t-1 (slot reuse), L1 f1>=t-2 (slot reuse)
//   L1(t): wait f0>=t+1 (h0[t] ready),      peers f1>=t-1 (slot reuse)
__global__ __launch_bounds__(256, 1) void lstm_persist(PP P) {
    __shared__ short8 WldsH[4096];   // Whh slice, 64 KB
    __shared__ short8 WldsI[4096];   // Wih slice, 64 KB (L0 uses 256 entries)

    const int bid   = blockIdx.x;
    const int gsw   = bid & 7;
    const bool isL0 = (gsw < 4);
    const int mg    = gsw & 3;
    const int jj    = bid >> 3;
    const int lb    = mg * 32 + jj;       // logical id within layer
    const int j0    = jj * 16;
    const int m0    = mg * 256;
    const int tid   = threadIdx.x;
    const int wid   = tid >> 6;
    const int lane  = tid & 63;

    // stage weight slices into LDS (frag-major)
    {
        const bf16* Whh = isL0 ? P.Whh0 : P.Whh1;
        for (int i = 0; i < 16; ++i) {
            int s = tid + i * 256;
            int frag = s >> 6, ln = s & 63;
            int ks = frag >> 2, g = frag & 3;
            WldsH[s] = *(const short8*)(Whh + (size_t)(g * H_ + j0 + (ln & 15)) * H_
                                        + ks * 32 + (ln >> 4) * 8);
        }
        if (isL0) {
            if (tid == (tid & 255)) { /* no-op */ }
            if (tid < 256) {
                int frag = tid >> 6, ln = tid & 63;
                int g = frag & 3;   // ks = 0
                WldsI[tid] = *(const short8*)(P.Wih0 + (size_t)(g * H_ + j0 + (ln & 15)) * F_
                                              + (ln >> 4) * 8);
            }
        } else {
            for (int i = 0; i < 16; ++i) {
                int s = tid + i * 256;
                int frag = s >> 6, ln = s & 63;
                int ks = frag >> 2, g = frag & 3;
                WldsI[s] = *(const short8*)(P.Wih1 + (size_t)(g * H_ + j0 + (ln & 15)) * H_
                                            + ks * 32 + (ln >> 4) * 8);
            }
        }
        __syncthreads();
    }

    float creg[16];
    #pragma unroll
    for (int i = 0; i < 16; ++i) creg[i] = 0.f;

    int* f0 = P.flags;
    int* f1 = P.flags + 128 * STRF;
    int* fy = P.flags + 256 * STRF;
    const int* f0g = f0 + mg * 32 * STRF;
    const int* f1g = f1 + mg * 32 * STRF;
    const int* fyg = fy + mg * 32 * STRF;

    if (isL0) {
        // encoder t = 0..149
        for (int t = 0; t < T_; ++t) {
            wait2(f0g, t - 1, f1g, t - 2);
            layer_step<1, 32>(P.seq + (size_t)t * B_ * F_,
                              P.h0 + (size_t)((t + 2) % 3) * BH, WldsH, WldsI, P.b0,
                              creg, P.h0 + (size_t)(t % 3) * BH, m0, j0, wid, lane);
            signal1(f0 + lb * STRF, t + 1);
        }
        // decoder: y-rounds interleaved with L0 steps
        for (int s = 0; s <= NSTEPS_; ++s) {
            wait2(f1g, T_ + s, nullptr, 0);
            {
                int id = lb * 256 + tid;        // b*32 + f
                int br = id >> 5, f = id & 31;
                const short8* hv = (const short8*)(P.h1 + (size_t)((T_ - 1 + s) % 3) * BH
                                                   + (size_t)br * H_);
                const short8* wv = (const short8*)(P.dwb + (size_t)f * H_);
                float acc = P.dec_b[f];
                for (int i = 0; i < H_ / 8; ++i) {
                    short8 h8 = hv[i], w8 = wv[i];
                    #pragma unroll
                    for (int k = 0; k < 8; ++k)
                        acc += b2f_(h8[k]) * b2f_(w8[k]);
                }
                P.y[id] = __float2bfloat16(acc);
                if (s >= 1)
                    P.fut[(size_t)br * (F_ * NSTEPS_) + f * NSTEPS_ + (s - 1)] = acc;
            }
            signal1(fy + lb * STRF, s + 1);
            if (s < NSTEPS_) {
                int t = T_ + s;
                wait2(f0g, t - 1, f1g, t - 2);
                wait2(fyg, s + 1, nullptr, 0);
                layer_step<1, 32>(P.y,
                                  P.h0 + (size_t)((t + 2) % 3) * BH, WldsH, WldsI, P.b0,
                                  creg, P.h0 + (size_t)(t % 3) * BH, m0, j0, wid, lane);
                signal1(f0 + lb * STRF, t + 1);
            }
        }
    } else {
        // layer 1: t = 0..159
        for (int t = 0; t < T_ + NSTEPS_; ++t) {
            wait2(f0g, t + 1, f1g, t - 1);
            layer_step<16, 512>(P.h0 + (size_t)(t % 3) * BH,
                                P.h1 + (size_t)((t + 2) % 3) * BH, WldsH, WldsI, P.b1,
                                creg, P.h1 + (size_t)(t % 3) * BH, m0, j0, wid, lane);
            signal1(f1 + lb * STRF, t + 1);
        }
    }
}

// ---------------------------------------------------------------------------
__global__ __launch_bounds__(256) void deconv_kernel(
    const float* __restrict__ fut, const float* __restrict__ dw,
    float* __restrict__ out)
{
    int idx = blockIdx.x * 256 + threadIdx.x;
    if (idx >= B_ * 49) return;
    int b = idx / 49, jj = idx % 49;
    int tlo = jj - (KD_ - 1); if (tlo < 0) tlo = 0;
    int thi = jj; if (thi > NSTEPS_ - 1) thi = NSTEPS_ - 1;
    float acc = 0.f;
    for (int f = 0; f < F_; ++f) {
        const float* fr = fut + (size_t)b * (F_ * NSTEPS_) + f * NSTEPS_;
        const float* wr = dw + f * KD_;
        for (int t = tlo; t <= thi; ++t)
            acc += fr[t] * wr[jj - t];
    }
    out[idx] = acc;
}

// ---------------------------------------------------------------------------
extern "C" void kernel_launch(void* const* d_in, const int* in_sizes, int n_in,
                              void* d_out, int out_size, void* d_ws, size_t ws_size,
                              hipStream_t stream) {
    const float* x       = (const float*)d_in[0];
    const float* conv_w  = (const float*)d_in[1];
    const float* conv_b  = (const float*)d_in[2];
    const float* Wih0f   = (const float*)d_in[3];
    const float* Whh0f   = (const float*)d_in[4];
    const float* bih0    = (const float*)d_in[5];
    const float* bhh0    = (const float*)d_in[6];
    const float* Wih1f   = (const float*)d_in[7];
    const float* Whh1f   = (const float*)d_in[8];
    const float* bih1    = (const float*)d_in[9];
    const float* bhh1    = (const float*)d_in[10];
    const float* dec_wf  = (const float*)d_in[11];
    const float* dec_b   = (const float*)d_in[12];
    const float* deconvw = (const float*)d_in[13];
    float* out = (float*)d_out;

    char* ws = (char*)d_ws;
    size_t off = 0;
    auto alloc = [&](size_t bytes) { char* p = ws + off; off = (off + bytes + 255) & ~(size_t)255; return p; };
    bf16*  seq   = (bf16*) alloc((size_t)T_ * B_ * F_ * 2);
    float* b0v   = (float*)alloc(G4H * 4);
    float* b1v   = (float*)alloc(G4H * 4);
    bf16*  h0    = (bf16*) alloc((size_t)3 * BH * 2);
    bf16*  h1    = (bf16*) alloc((size_t)3 * BH * 2);
    bf16*  y     = (bf16*) alloc((size_t)B_ * F_ * 2);
    float* fut   = (float*)alloc((size_t)B_ * F_ * NSTEPS_ * 4);
    bf16*  Wih0b = (bf16*) alloc((size_t)G4H * F_ * 2);
    bf16*  Whh0b = (bf16*) alloc((size_t)G4H * H_ * 2);
    bf16*  Wih1b = (bf16*) alloc((size_t)G4H * H_ * 2);
    bf16*  Whh1b = (bf16*) alloc((size_t)G4H * H_ * 2);
    bf16*  dec_wb= (bf16*) alloc((size_t)F_ * H_ * 2);
    int*   flags = (int*)  alloc(3 * 128 * STRF * 4);

    hipMemsetAsync(h0, 0, (size_t)3 * BH * 2, stream);
    hipMemsetAsync(h1, 0, (size_t)3 * BH * 2, stream);
    hipMemsetAsync(flags, 0, 3 * 128 * STRF * 4, stream);

    cvt_kernel<<<(G4H * F_ + 255) / 256, 256, 0, stream>>>(Wih0f, Wih0b, G4H * F_);
    cvt_kernel<<<(G4H * H_ + 255) / 256, 256, 0, stream>>>(Whh0f, Whh0b, G4H * H_);
    cvt_kernel<<<(G4H * H_ + 255) / 256, 256, 0, stream>>>(Wih1f, Wih1b, G4H * H_);
    cvt_kernel<<<(G4H * H_ + 255) / 256, 256, 0, stream>>>(Whh1f, Whh1b, G4H * H_);
    cvt_kernel<<<(F_ * H_ + 255) / 256, 256, 0, stream>>>(dec_wf, dec_wb, F_ * H_);

    bias_kernel<<<16, 256, 0, stream>>>(bih0, bhh0, bih1, bhh1, b0v, b1v);
    conv_kernel<<<B_, 256, 0, stream>>>(x, conv_w, conv_b, seq);

    PP P;
    P.seq = seq; P.Wih0 = Wih0b; P.Whh0 = Whh0b; P.Wih1 = Wih1b; P.Whh1 = Whh1b;
    P.dwb = dec_wb; P.b0 = b0v; P.b1 = b1v; P.dec_b = dec_b;
    P.fut = fut; P.h0 = h0; P.h1 = h1; P.y = y;
    P.flags = flags;

    void* args[] = { &P };
    hipError_t err = hipLaunchCooperativeKernel((const void*)lstm_persist,
                                                dim3(256), dim3(256), args, 0, stream);
    if (err != hipSuccess) {
        lstm_persist<<<256, 256, 0, stream>>>(P);
    }

    deconv_kernel<<<196, 256, 0, stream>>>(fut, deconvw, out);
}

// Round 7
// 4869.759 us; speedup vs baseline: 3.2623x; 1.5140x over previous
//
#include <hip/hip_runtime.h>
#include <hip/hip_bf16.h>

typedef __hip_bfloat16 bf16;
typedef __attribute__((ext_vector_type(8))) short short8;
typedef __attribute__((ext_vector_type(4))) float float4v;

#define B_    1024
#define H_    512
#define G4H   2048
#define F_    32
#define CIN_  4
#define K_    30
#define STRIDE_ 6
#define L_    924
#define T_    150
#define KD_   40
#define NSTEPS_ 10
#define BH    (B_ * H_)
#define STRF  16   // ints between flags = 64B (one cacheline per flag)

__device__ __forceinline__ float sigmoidf_(float x) { return 1.f / (1.f + __expf(-x)); }
__device__ __forceinline__ float tanhf_(float x)    { return 1.f - 2.f / (__expf(2.f * x) + 1.f); }
__device__ __forceinline__ float b2f_(short s) {
    return __uint_as_float(((unsigned)(unsigned short)s) << 16);
}
// write-through (agent-scope) bf16 store: no dirty L2 line -> no wbl2 needed
__device__ __forceinline__ void stwt_(bf16* p, float v) {
    union { __hip_bfloat16 b; unsigned short u; } cv;
    cv.b = __float2bfloat16(v);
    __hip_atomic_store((unsigned short*)p, cv.u, __ATOMIC_RELAXED, __HIP_MEMORY_SCOPE_AGENT);
}

// ---------------------------------------------------------------------------
__global__ __launch_bounds__(256) void cvt_kernel(const float* __restrict__ src,
                                                  bf16* __restrict__ dst, int n) {
    int i = blockIdx.x * 256 + threadIdx.x;
    if (i < n) dst[i] = __float2bfloat16(src[i]);
}

__global__ void bias_kernel(const float* __restrict__ bih0, const float* __restrict__ bhh0,
                            const float* __restrict__ bih1, const float* __restrict__ bhh1,
                            float* __restrict__ b0, float* __restrict__ b1) {
    int i = blockIdx.x * 256 + threadIdx.x;
    if (i < G4H)      b0[i] = bih0[i] + bhh0[i];
    else if (i < 2*G4H) { int j = i - G4H; b1[j] = bih1[j] + bhh1[j]; }
}

// ---------------------------------------------------------------------------
__global__ __launch_bounds__(256) void conv_kernel(
    const float* __restrict__ x, const float* __restrict__ w,
    const float* __restrict__ cb, bf16* __restrict__ seq)
{
    __shared__ float w_lds[CIN_ * K_ * F_];
    __shared__ float x_lds[CIN_ * L_];
    int tid = threadIdx.x;
    int b = blockIdx.x;
    for (int i = tid; i < CIN_ * K_ * F_; i += 256) {
        int f = i & 31, r = i >> 5;
        w_lds[r * 32 + f] = w[f * (CIN_ * K_) + r];
    }
    const float* xb = x + (size_t)b * (CIN_ * L_);
    for (int i = tid; i < CIN_ * L_; i += 256)
        x_lds[i] = xb[i];
    __syncthreads();
    int f = tid & 31, tt = tid >> 5;
    float cbf = cb[f];
    for (int t0 = 0; t0 < T_; t0 += 8) {
        int t = t0 + tt;
        if (t < T_) {
            float acc = cbf;
            #pragma unroll
            for (int c = 0; c < CIN_; ++c) {
                const float* xr = x_lds + c * L_ + t * STRIDE_;
                const float* wr = w_lds + c * K_ * 32 + f;
                #pragma unroll
                for (int k = 0; k < K_; ++k)
                    acc += xr[k] * wr[k * 32];
            }
            acc = fmaxf(acc, 0.f);
            seq[(size_t)t * (B_ * F_) + b * F_ + f] = __float2bfloat16(acc);
        }
    }
}

// ---------------------------------------------------------------------------
// sync: padded per-block flags; release = barrier-drained stores + waitcnt +
// relaxed agent store (producers write through, so no L2 writeback needed).
// acquire = relaxed poll + buffer_inv (acquire fence, invalidate-only).
// ---------------------------------------------------------------------------
__device__ __forceinline__ void wait2(const int* fa, int ta, const int* fb, int tb) {
    const int t = threadIdx.x;
    if (t < 64) {
        const int* p = nullptr; int tgt = 0;
        if (t < 32) { if (fa) { p = fa + t * STRF;        tgt = ta; } }
        else        { if (fb) { p = fb + (t - 32) * STRF; tgt = tb; } }
        for (;;) {
            int v = p ? __hip_atomic_load(p, __ATOMIC_RELAXED, __HIP_MEMORY_SCOPE_AGENT)
                      : 0x7fffffff;
            if (__all(v >= tgt)) break;
            __builtin_amdgcn_s_sleep(2);
        }
    }
    __syncthreads();
    __builtin_amdgcn_fence(__ATOMIC_ACQUIRE, "agent");   // buffer_inv, no wbl2
}

__device__ __forceinline__ void signal1(int* f, int val) {
    __syncthreads();                       // all waves' stores drained at barrier
    if (threadIdx.x == 0) {
        __builtin_amdgcn_s_waitcnt(0);     // own stores acked at coherent point
        __hip_atomic_store(f, val, __ATOMIC_RELAXED, __HIP_MEMORY_SCOPE_AGENT);
    }
}

// ---------------------------------------------------------------------------
// One layer step for (m0: 256 rows) x (j0: 16 cols, 4 gates).
// Wih AND Whh LDS-resident. C state in registers. Hout written write-through.
// ---------------------------------------------------------------------------
template<int P1KS, int XSTR>
__device__ __forceinline__ void layer_step(
    const bf16* __restrict__ X, const bf16* __restrict__ Hprev,
    const short8* __restrict__ WldsH, const short8* __restrict__ WldsI,
    const float* __restrict__ bias, float (&creg)[16], bf16* __restrict__ Hout,
    int m0, int j0, int wid, int lane)
{
    const int row16 = lane & 15;
    const int quad  = lane >> 4;
    const int mrow  = m0 + wid * 64 + row16;

    float4v acc[4][4];
    #pragma unroll
    for (int ms = 0; ms < 4; ++ms)
        #pragma unroll
        for (int g = 0; g < 4; ++g)
            acc[ms][g] = (float4v){0.f, 0.f, 0.f, 0.f};

    // part 1: X @ Wih^T (B from LDS)
    for (int ks = 0; ks < P1KS; ++ks) {
        short8 av[4];
        #pragma unroll
        for (int ms = 0; ms < 4; ++ms)
            av[ms] = *(const short8*)(X + (size_t)(mrow + ms * 16) * XSTR
                                      + ks * 32 + quad * 8);
        #pragma unroll
        for (int g = 0; g < 4; ++g) {
            short8 bfr = WldsI[(ks * 4 + g) * 64 + lane];
            #pragma unroll
            for (int ms = 0; ms < 4; ++ms)
                acc[ms][g] = __builtin_amdgcn_mfma_f32_16x16x32_bf16(av[ms], bfr, acc[ms][g], 0, 0, 0);
        }
    }

    // part 2: Hprev @ Whh^T (B from LDS)
    for (int ks = 0; ks < 16; ++ks) {
        short8 av[4];
        #pragma unroll
        for (int ms = 0; ms < 4; ++ms)
            av[ms] = *(const short8*)(Hprev + (size_t)(mrow + ms * 16) * H_
                                      + ks * 32 + quad * 8);
        #pragma unroll
        for (int g = 0; g < 4; ++g) {
            short8 bfr = WldsH[(ks * 4 + g) * 64 + lane];
            #pragma unroll
            for (int ms = 0; ms < 4; ++ms)
                acc[ms][g] = __builtin_amdgcn_mfma_f32_16x16x32_bf16(av[ms], bfr, acc[ms][g], 0, 0, 0);
        }
    }

    // epilogue: c in registers; h written write-through (agent visible)
    const int j = j0 + row16;
    const float bi  = bias[j];
    const float bff = bias[H_ + j];
    const float bg  = bias[2 * H_ + j];
    const float bo  = bias[3 * H_ + j];
    #pragma unroll
    for (int ms = 0; ms < 4; ++ms) {
        #pragma unroll
        for (int r = 0; r < 4; ++r) {
            int brow = m0 + wid * 64 + ms * 16 + quad * 4 + r;
            float ig = sigmoidf_(acc[ms][0][r] + bi);
            float fg = sigmoidf_(acc[ms][1][r] + bff);
            float gg = tanhf_(acc[ms][2][r] + bg);
            float og = sigmoidf_(acc[ms][3][r] + bo);
            float cn = fg * creg[ms * 4 + r] + ig * gg;
            creg[ms * 4 + r] = cn;
            stwt_(Hout + (size_t)brow * H_ + j, og * tanhf_(cn));
        }
    }
}

// ---------------------------------------------------------------------------
struct PP {
    const bf16 *seq, *Wih0, *Whh0, *Wih1, *Whh1, *dwb;
    const float *b0, *b1, *dec_b;
    float *fut;
    bf16 *h0, *h1, *y;       // h0/h1: 3 slots of [B,H] each
    int *flags;              // f0[128], f1[128], fy[128], 64B apart
};

// Persistent kernel, 256 blocks (1/CU). Swizzle: bid = jj*8 + layer*4 + mg
// puts each (layer,mg) 32-block peer group (shares h-slice reads) on one XCD.
// flag value = t+1 after step t. 3 h-slots (slot = t%3). Waits:
//   L0(t): f0>=t   (peers' h0[t-1] ready + slot safety), f1>=t-2 (slot safety)
//   L1(t): f0>=t+1 (h0[t] ready), f1>=t (peers' h1[t-1] ready + slot safety)
//   y-round s: f1>=T+s (h1[T-1+s] ready), f0>=T+s for s>=1 (y slot consumed)
__global__ __launch_bounds__(256, 1) void lstm_persist(PP P) {
    __shared__ short8 WldsH[4096];   // Whh slice, 64 KB
    __shared__ short8 WldsI[4096];   // Wih slice, 64 KB (L0 uses 256 entries)

    const int bid   = blockIdx.x;
    const int gsw   = bid & 7;
    const bool isL0 = (gsw < 4);
    const int mg    = gsw & 3;
    const int jj    = bid >> 3;
    const int lb    = mg * 32 + jj;       // logical id within layer
    const int j0    = jj * 16;
    const int m0    = mg * 256;
    const int tid   = threadIdx.x;
    const int wid   = tid >> 6;
    const int lane  = tid & 63;

    // stage weight slices into LDS (frag-major)
    {
        const bf16* Whh = isL0 ? P.Whh0 : P.Whh1;
        for (int i = 0; i < 16; ++i) {
            int s = tid + i * 256;
            int frag = s >> 6, ln = s & 63;
            int ks = frag >> 2, g = frag & 3;
            WldsH[s] = *(const short8*)(Whh + (size_t)(g * H_ + j0 + (ln & 15)) * H_
                                        + ks * 32 + (ln >> 4) * 8);
        }
        if (isL0) {
            if (tid < 256) {
                int frag = tid >> 6, ln = tid & 63;
                int g = frag & 3;   // ks = 0
                WldsI[tid] = *(const short8*)(P.Wih0 + (size_t)(g * H_ + j0 + (ln & 15)) * F_
                                              + (ln >> 4) * 8);
            }
        } else {
            for (int i = 0; i < 16; ++i) {
                int s = tid + i * 256;
                int frag = s >> 6, ln = s & 63;
                int ks = frag >> 2, g = frag & 3;
                WldsI[s] = *(const short8*)(P.Wih1 + (size_t)(g * H_ + j0 + (ln & 15)) * H_
                                            + ks * 32 + (ln >> 4) * 8);
            }
        }
        __syncthreads();
    }

    float creg[16];
    #pragma unroll
    for (int i = 0; i < 16; ++i) creg[i] = 0.f;

    int* f0 = P.flags;
    int* f1 = P.flags + 128 * STRF;
    int* fy = P.flags + 256 * STRF;
    const int* f0g = f0 + mg * 32 * STRF;
    const int* f1g = f1 + mg * 32 * STRF;
    const int* fyg = fy + mg * 32 * STRF;

    if (isL0) {
        // encoder t = 0..149
        for (int t = 0; t < T_; ++t) {
            wait2(f0g, t, f1g, t - 2);
            layer_step<1, 32>(P.seq + (size_t)t * B_ * F_,
                              P.h0 + (size_t)((t + 2) % 3) * BH, WldsH, WldsI, P.b0,
                              creg, P.h0 + (size_t)(t % 3) * BH, m0, j0, wid, lane);
            signal1(f0 + lb * STRF, t + 1);
        }
        // decoder: y-rounds interleaved with L0 steps
        for (int s = 0; s <= NSTEPS_; ++s) {
            wait2(f1g, T_ + s, (s >= 1) ? f0g : nullptr, T_ + s);
            {
                int id = lb * 256 + tid;        // b*32 + f
                int br = id >> 5, f = id & 31;
                const short8* hv = (const short8*)(P.h1 + (size_t)((T_ - 1 + s) % 3) * BH
                                                   + (size_t)br * H_);
                const short8* wv = (const short8*)(P.dwb + (size_t)f * H_);
                float acc = P.dec_b[f];
                for (int i = 0; i < H_ / 8; ++i) {
                    short8 h8 = hv[i], w8 = wv[i];
                    #pragma unroll
                    for (int k = 0; k < 8; ++k)
                        acc += b2f_(h8[k]) * b2f_(w8[k]);
                }
                stwt_(P.y + id, acc);
                if (s >= 1)
                    P.fut[(size_t)br * (F_ * NSTEPS_) + f * NSTEPS_ + (s - 1)] = acc;
            }
            signal1(fy + lb * STRF, s + 1);
            if (s < NSTEPS_) {
                int t = T_ + s;
                wait2(f0g, t, f1g, t - 2);
                wait2(fyg, s + 1, nullptr, 0);
                layer_step<1, 32>(P.y,
                                  P.h0 + (size_t)((t + 2) % 3) * BH, WldsH, WldsI, P.b0,
                                  creg, P.h0 + (size_t)(t % 3) * BH, m0, j0, wid, lane);
                signal1(f0 + lb * STRF, t + 1);
            }
        }
    } else {
        // layer 1: t = 0..159
        for (int t = 0; t < T_ + NSTEPS_; ++t) {
            wait2(f0g, t + 1, f1g, t);
            layer_step<16, 512>(P.h0 + (size_t)(t % 3) * BH,
                                P.h1 + (size_t)((t + 2) % 3) * BH, WldsH, WldsI, P.b1,
                                creg, P.h1 + (size_t)(t % 3) * BH, m0, j0, wid, lane);
            signal1(f1 + lb * STRF, t + 1);
        }
    }
}

// ---------------------------------------------------------------------------
__global__ __launch_bounds__(256) void deconv_kernel(
    const float* __restrict__ fut, const float* __restrict__ dw,
    float* __restrict__ out)
{
    int idx = blockIdx.x * 256 + threadIdx.x;
    if (idx >= B_ * 49) return;
    int b = idx / 49, jj = idx % 49;
    int tlo = jj - (KD_ - 1); if (tlo < 0) tlo = 0;
    int thi = jj; if (thi > NSTEPS_ - 1) thi = NSTEPS_ - 1;
    float acc = 0.f;
    for (int f = 0; f < F_; ++f) {
        const float* fr = fut + (size_t)b * (F_ * NSTEPS_) + f * NSTEPS_;
        const float* wr = dw + f * KD_;
        for (int t = tlo; t <= thi; ++t)
            acc += fr[t] * wr[jj - t];
    }
    out[idx] = acc;
}

// ---------------------------------------------------------------------------
extern "C" void kernel_launch(void* const* d_in, const int* in_sizes, int n_in,
                              void* d_out, int out_size, void* d_ws, size_t ws_size,
                              hipStream_t stream) {
    const float* x       = (const float*)d_in[0];
    const float* conv_w  = (const float*)d_in[1];
    const float* conv_b  = (const float*)d_in[2];
    const float* Wih0f   = (const float*)d_in[3];
    const float* Whh0f   = (const float*)d_in[4];
    const float* bih0    = (const float*)d_in[5];
    const float* bhh0    = (const float*)d_in[6];
    const float* Wih1f   = (const float*)d_in[7];
    const float* Whh1f   = (const float*)d_in[8];
    const float* bih1    = (const float*)d_in[9];
    const float* bhh1    = (const float*)d_in[10];
    const float* dec_wf  = (const float*)d_in[11];
    const float* dec_b   = (const float*)d_in[12];
    const float* deconvw = (const float*)d_in[13];
    float* out = (float*)d_out;

    char* ws = (char*)d_ws;
    size_t off = 0;
    auto alloc = [&](size_t bytes) { char* p = ws + off; off = (off + bytes + 255) & ~(size_t)255; return p; };
    bf16*  seq   = (bf16*) alloc((size_t)T_ * B_ * F_ * 2);
    float* b0v   = (float*)alloc(G4H * 4);
    float* b1v   = (float*)alloc(G4H * 4);
    bf16*  h0    = (bf16*) alloc((size_t)3 * BH * 2);
    bf16*  h1    = (bf16*) alloc((size_t)3 * BH * 2);
    bf16*  y     = (bf16*) alloc((size_t)B_ * F_ * 2);
    float* fut   = (float*)alloc((size_t)B_ * F_ * NSTEPS_ * 4);
    bf16*  Wih0b = (bf16*) alloc((size_t)G4H * F_ * 2);
    bf16*  Whh0b = (bf16*) alloc((size_t)G4H * H_ * 2);
    bf16*  Wih1b = (bf16*) alloc((size_t)G4H * H_ * 2);
    bf16*  Whh1b = (bf16*) alloc((size_t)G4H * H_ * 2);
    bf16*  dec_wb= (bf16*) alloc((size_t)F_ * H_ * 2);
    int*   flags = (int*)  alloc(3 * 128 * STRF * 4);

    hipMemsetAsync(h0, 0, (size_t)3 * BH * 2, stream);
    hipMemsetAsync(h1, 0, (size_t)3 * BH * 2, stream);
    hipMemsetAsync(flags, 0, 3 * 128 * STRF * 4, stream);

    cvt_kernel<<<(G4H * F_ + 255) / 256, 256, 0, stream>>>(Wih0f, Wih0b, G4H * F_);
    cvt_kernel<<<(G4H * H_ + 255) / 256, 256, 0, stream>>>(Whh0f, Whh0b, G4H * H_);
    cvt_kernel<<<(G4H * H_ + 255) / 256, 256, 0, stream>>>(Wih1f, Wih1b, G4H * H_);
    cvt_kernel<<<(G4H * H_ + 255) / 256, 256, 0, stream>>>(Whh1f, Whh1b, G4H * H_);
    cvt_kernel<<<(F_ * H_ + 255) / 256, 256, 0, stream>>>(dec_wf, dec_wb, F_ * H_);

    bias_kernel<<<16, 256, 0, stream>>>(bih0, bhh0, bih1, bhh1, b0v, b1v);
    conv_kernel<<<B_, 256, 0, stream>>>(x, conv_w, conv_b, seq);

    PP P;
    P.seq = seq; P.Wih0 = Wih0b; P.Whh0 = Whh0b; P.Wih1 = Wih1b; P.Whh1 = Whh1b;
    P.dwb = dec_wb; P.b0 = b0v; P.b1 = b1v; P.dec_b = dec_b;
    P.fut = fut; P.h0 = h0; P.h1 = h1; P.y = y;
    P.flags = flags;

    void* args[] = { &P };
    hipError_t err = hipLaunchCooperativeKernel((const void*)lstm_persist,
                                                dim3(256), dim3(256), args, 0, stream);
    if (err != hipSuccess) {
        lstm_persist<<<256, 256, 0, stream>>>(P);
    }

    deconv_kernel<<<196, 256, 0, stream>>>(fut, deconvw, out);
}